// Round 2
// baseline (4602.384 us; speedup 1.0000x reference)
//
#include <hip/hip_runtime.h>
#include <hip/hip_bf16.h>
#include <cmath>

typedef __attribute__((ext_vector_type(8))) short short8;
typedef __attribute__((ext_vector_type(4))) short short4_t;
typedef __attribute__((ext_vector_type(4))) float float4_t;

__device__ __forceinline__ float bf2f(unsigned short u) {
    union { unsigned int i; float f; } v; v.i = ((unsigned int)u) << 16; return v.f;
}
__device__ __forceinline__ unsigned short f2bf(float f) {
    union { float f; unsigned int i; } v; v.f = f;
    unsigned int r = v.i + 0x7FFF + ((v.i >> 16) & 1);  // round-to-nearest-even
    return (unsigned short)(r >> 16);
}
__device__ __forceinline__ float sigm(float x) { return 1.f / (1.f + __expf(-x)); }

__device__ __forceinline__ short8 ld_frag8(const unsigned short* p) {
    short4_t a = *reinterpret_cast<const short4_t*>(p);
    short4_t b = *reinterpret_cast<const short4_t*>(p + 4);
    short8 v;
    v[0]=a[0]; v[1]=a[1]; v[2]=a[2]; v[3]=a[3];
    v[4]=b[0]; v[5]=b[1]; v[6]=b[2]; v[7]=b[3];
    return v;
}

// ---------------- prep kernels ----------------

// in: fp32 [R][C]  ->  out: bf16 [C][R]
__global__ void k_transpose_bf16(const float* __restrict__ in, unsigned short* __restrict__ out, int R, int C) {
    __shared__ float tile[32][33];
    int c0 = blockIdx.x * 32, r0 = blockIdx.y * 32;
    int tx = threadIdx.x, ty = threadIdx.y;  // 32 x 8
#pragma unroll
    for (int i = 0; i < 4; i++)
        tile[ty + i * 8][tx] = in[(size_t)(r0 + ty + i * 8) * C + c0 + tx];
    __syncthreads();
#pragma unroll
    for (int i = 0; i < 4; i++)
        out[(size_t)(c0 + ty + i * 8) * R + r0 + tx] = f2bf(tile[tx][ty + i * 8]);
}

// W_h [1024][4096] fp32 -> fragment-ordered bf16 pack:
// out[((nfrag*32+ks)*64+lane)*8+e] = Wh[ks*32+8*(lane>>4)+e][(nfrag&3)*1024+(nfrag>>2)*16+(lane&15)]
__global__ void k_pack_wh(const float* __restrict__ Wh, unsigned short* __restrict__ out) {
    int gid = blockIdx.x * 256 + threadIdx.x;  // 524288 = 256 nfrag * 32 ks * 64 lane
    int lane = gid & 63, ks = (gid >> 6) & 31, nfrag = gid >> 11;
    int col = (nfrag & 3) * 1024 + ((nfrag >> 2) << 4) + (lane & 15);
    int kb = ks * 32 + ((lane >> 4) << 3);
    short8 v;
#pragma unroll
    for (int e = 0; e < 8; e++) v[e] = (short)f2bf(Wh[(size_t)(kb + e) * 4096 + col]);
    *reinterpret_cast<short8*>(out + (size_t)gid * 8) = v;
}

__global__ void k_bias(const float* __restrict__ bi, const float* __restrict__ bh, float* __restrict__ bs) {
    int i = blockIdx.x * 256 + threadIdx.x;
    if (i < 4096) bs[i] = bi[i] + bh[i];
}

// ---------------- GEMM1 (chunked): xgc[b*c + s][n] = sum_k text[b*512+s0+s][k] * WinT[n][k]
// A fp32 (converted to bf16 while staging), BT bf16 pre-transposed. N=4096, K=768.
__global__ __launch_bounds__(256) void k_gemm1(
    const float* __restrict__ A,
    const unsigned short* __restrict__ BT,
    unsigned short* __restrict__ C,
    int s0, int log2c)
{
    __shared__ unsigned short Asl[128 * 40];
    __shared__ unsigned short Bsl[128 * 40];
    const int K = 768, N = 4096;
    int t = threadIdx.x, lane = t & 63, w = t >> 6;
    int m0 = blockIdx.y * 128, n0 = blockIdx.x * 128;
    int wm = (w >> 1) * 64, wn = (w & 1) * 64;
    int cmask = (1 << log2c) - 1;
    float4_t acc[4][4] = {};

    for (int k0 = 0; k0 < K; k0 += 32) {
        __syncthreads();
#pragma unroll
        for (int p = 0; p < 2; p++) {
            int flat = p * 256 + t;          // 0..511 : 128 rows x 4 quads of 8
            int row = flat >> 2, kq = flat & 3;
            int row_l = m0 + row;
            int b = row_l >> log2c, s = row_l & cmask;
            const float* ap = A + (size_t)(b * 512 + s0 + s) * K + k0 + kq * 8;
            float4 v0 = *reinterpret_cast<const float4*>(ap);
            float4 v1 = *reinterpret_cast<const float4*>(ap + 4);
            short4_t o0, o1;
            o0[0]=(short)f2bf(v0.x); o0[1]=(short)f2bf(v0.y); o0[2]=(short)f2bf(v0.z); o0[3]=(short)f2bf(v0.w);
            o1[0]=(short)f2bf(v1.x); o1[1]=(short)f2bf(v1.y); o1[2]=(short)f2bf(v1.z); o1[3]=(short)f2bf(v1.w);
            *reinterpret_cast<short4_t*>(&Asl[row * 40 + kq * 8]) = o0;
            *reinterpret_cast<short4_t*>(&Asl[row * 40 + kq * 8 + 4]) = o1;
            short8 vb = *reinterpret_cast<const short8*>(BT + (size_t)(n0 + row) * K + k0 + kq * 8);
            const short4_t* wp = reinterpret_cast<const short4_t*>(&vb);
            *reinterpret_cast<short4_t*>(&Bsl[row * 40 + kq * 8]) = wp[0];
            *reinterpret_cast<short4_t*>(&Bsl[row * 40 + kq * 8 + 4]) = wp[1];
        }
        __syncthreads();
        short8 af[4], bfr[4];
#pragma unroll
        for (int mi = 0; mi < 4; mi++)
            af[mi] = ld_frag8(&Asl[(wm + mi * 16 + (lane & 15)) * 40 + (lane >> 4) * 8]);
#pragma unroll
        for (int ni = 0; ni < 4; ni++)
            bfr[ni] = ld_frag8(&Bsl[(wn + ni * 16 + (lane & 15)) * 40 + (lane >> 4) * 8]);
#pragma unroll
        for (int mi = 0; mi < 4; mi++)
#pragma unroll
            for (int ni = 0; ni < 4; ni++)
                acc[mi][ni] = __builtin_amdgcn_mfma_f32_16x16x32_bf16(af[mi], bfr[ni], acc[mi][ni], 0, 0, 0);
    }

#pragma unroll
    for (int mi = 0; mi < 4; mi++)
#pragma unroll
        for (int ni = 0; ni < 4; ni++)
#pragma unroll
            for (int r = 0; r < 4; r++) {
                int row = m0 + wm + mi * 16 + (lane >> 4) * 4 + r;
                int col = n0 + wn + ni * 16 + (lane & 15);
                C[(size_t)row * N + col] = f2bf(acc[mi][ni][r]);
            }
}

// ---------------- generic bf16 GEMM: C[M][N] = A[M][K] * BT[N][K] ----------------
__global__ __launch_bounds__(256) void k_gemm_bf16(
    const unsigned short* __restrict__ A,
    const unsigned short* __restrict__ BT,
    unsigned short* __restrict__ C,
    int M, int N, int K)
{
    __shared__ unsigned short Asl[128 * 40];
    __shared__ unsigned short Bsl[128 * 40];
    int t = threadIdx.x, lane = t & 63, w = t >> 6;
    int m0 = blockIdx.y * 128, n0 = blockIdx.x * 128;
    int wm = (w >> 1) * 64, wn = (w & 1) * 64;
    float4_t acc[4][4] = {};

    for (int k0 = 0; k0 < K; k0 += 32) {
        __syncthreads();
#pragma unroll
        for (int p = 0; p < 2; p++) {
            int flat = p * 256 + t;
            int row = flat >> 2, kq = flat & 3;
            short8 va = *reinterpret_cast<const short8*>(A + (size_t)(m0 + row) * K + k0 + kq * 8);
            const short4_t* vp = reinterpret_cast<const short4_t*>(&va);
            *reinterpret_cast<short4_t*>(&Asl[row * 40 + kq * 8]) = vp[0];
            *reinterpret_cast<short4_t*>(&Asl[row * 40 + kq * 8 + 4]) = vp[1];
            short8 vb = *reinterpret_cast<const short8*>(BT + (size_t)(n0 + row) * K + k0 + kq * 8);
            const short4_t* wp = reinterpret_cast<const short4_t*>(&vb);
            *reinterpret_cast<short4_t*>(&Bsl[row * 40 + kq * 8]) = wp[0];
            *reinterpret_cast<short4_t*>(&Bsl[row * 40 + kq * 8 + 4]) = wp[1];
        }
        __syncthreads();
        short8 af[4], bfr[4];
#pragma unroll
        for (int mi = 0; mi < 4; mi++)
            af[mi] = ld_frag8(&Asl[(wm + mi * 16 + (lane & 15)) * 40 + (lane >> 4) * 8]);
#pragma unroll
        for (int ni = 0; ni < 4; ni++)
            bfr[ni] = ld_frag8(&Bsl[(wn + ni * 16 + (lane & 15)) * 40 + (lane >> 4) * 8]);
#pragma unroll
        for (int mi = 0; mi < 4; mi++)
#pragma unroll
            for (int ni = 0; ni < 4; ni++)
                acc[mi][ni] = __builtin_amdgcn_mfma_f32_16x16x32_bf16(af[mi], bfr[ni], acc[mi][ni], 0, 0, 0);
    }

#pragma unroll
    for (int mi = 0; mi < 4; mi++)
#pragma unroll
        for (int ni = 0; ni < 4; ni++)
#pragma unroll
            for (int r = 0; r < 4; r++) {
                int row = m0 + wm + mi * 16 + (lane >> 4) * 4 + r;
                int col = n0 + wn + ni * 16 + (lane & 15);
                C[(size_t)row * N + col] = f2bf(acc[mi][ni][r]);
            }
}

// ---------------- LSTM step ----------------
// grid 128 = 64 unit-tiles x 2 batch-halves; block 512 = 8 waves = 2 batch-quarters x 4 gates
__global__ __launch_bounds__(512) void k_lstm_step(
    const unsigned short* __restrict__ xgc,     // [64*c][4096] bf16 (chunk)
    const unsigned short* __restrict__ WhPack,  // frag-ordered
    const float* __restrict__ bias_sum,         // [4096]
    const unsigned short* __restrict__ h_in,    // [64][1024] bf16
    unsigned short* __restrict__ h_out,         // [64][1024] bf16
    float* __restrict__ h_f32,                  // [64][1024]
    float* __restrict__ c_f32,                  // [64][1024]
    unsigned short* __restrict__ hs,            // [64*512][1024] bf16
    int tstep, int tl, int log2c)
{
    __shared__ unsigned short hstage[2 * 16 * 512];  // 32KB
    __shared__ float gate_lds[32 * 16 * 5];          // 10KB

    int t = threadIdx.x, lane = t & 63, w = t >> 6;
    int g = w & 3, mq = w >> 2;
    int ut = blockIdx.x >> 1, mh = blockIdx.x & 1;
    int j0 = ut * 16, rowbase = mh * 32;
    int nfrag = ut * 4 + g;
    int u = lane & 15;
    int colc = g * 1024 + j0 + u;

    float bsv = bias_sum[colc];
    float xgv[4];
#pragma unroll
    for (int r = 0; r < 4; r++) {
        int brow = rowbase + mq * 16 + (lane >> 4) * 4 + r;
        xgv[r] = bf2f(xgc[((size_t)((brow << log2c) + tl)) * 4096 + colc]);
    }

    float4_t acc = {0.f, 0.f, 0.f, 0.f};
    for (int kh = 0; kh < 2; kh++) {
        __syncthreads();
        if (w < 2) {
#pragma unroll
            for (int i = 0; i < 16; i++) {
                int row = rowbase + w * 16 + i;
                short8 v = *reinterpret_cast<const short8*>(h_in + (row << 10) + (kh << 9) + lane * 8);
                int bo = (lane * 16) ^ ((i & 7) << 4);
                *reinterpret_cast<short8*>(&hstage[w * 8192 + i * 512 + (bo >> 1)]) = v;
            }
        }
        __syncthreads();
#pragma unroll 4
        for (int ks = 0; ks < 16; ks++) {
            int rr = lane & 15;
            int bo = ((ks << 6) + ((lane >> 4) << 4)) ^ ((rr & 7) << 4);
            short8 a = *reinterpret_cast<const short8*>(&hstage[mq * 8192 + rr * 512 + (bo >> 1)]);
            short8 b = *reinterpret_cast<const short8*>(
                WhPack + (((size_t)(nfrag * 32 + (kh << 4) + ks)) << 9) + lane * 8);
            acc = __builtin_amdgcn_mfma_f32_16x16x32_bf16(a, b, acc, 0, 0, 0);
        }
    }

#pragma unroll
    for (int r = 0; r < 4; r++) {
        float vv = acc[r] + bsv + xgv[r];
        float av = (g == 2) ? tanhf(vv) : sigm(vv);
        int m_local = mq * 16 + (lane >> 4) * 4 + r;
        gate_lds[(m_local * 16 + u) * 5 + g] = av;
    }
    __syncthreads();

    int ml = t >> 4, u2 = t & 15;
    int base = (ml * 16 + u2) * 5;
    float rt = gate_lds[base + 0];
    float ft = gate_lds[base + 1];
    float gt = gate_lds[base + 2];
    float ot = gate_lds[base + 3];
    int b = rowbase + ml;
    int j = j0 + u2;
    float cold = c_f32[b * 1024 + j];
    float cn = ft * cold + rt * gt;
    float hn = ot * tanhf(cn);
    c_f32[b * 1024 + j] = cn;
    h_f32[b * 1024 + j] = hn;
    unsigned short hb = f2bf(hn);
    h_out[b * 1024 + j] = hb;
    hs[((size_t)(b * 512 + tstep)) * 1024 + j] = hb;
}

// ---------------- tail kernels ----------------

__global__ void k_fh(const float* __restrict__ h, const float* __restrict__ Wlo,
                     const float* __restrict__ blo, float* __restrict__ fh) {
    int gid = blockIdx.x * 256 + threadIdx.x;  // 32768
    int b = gid >> 9, d = gid & 511;
    float acc = blo[d];
    for (int k = 0; k < 1024; k++) acc += h[b * 1024 + k] * Wlo[k * 512 + d];
    fh[gid] = acc;
}

__global__ void k_wsb(const float* __restrict__ fh, const float* __restrict__ Was,
                      const float* __restrict__ bas, float* __restrict__ WSb) {
    int gid = blockIdx.x * 256 + threadIdx.x;  // 16384
    int b = gid >> 8, v = gid & 255;
    float acc = bas[v];
    for (int k = 0; k < 512; k++) acc += fh[b * 512 + k] * Was[k * 256 + v];
    WSb[gid] = acc;
}

__global__ void k_score(const unsigned short* __restrict__ WH, const float* __restrict__ bah,
                        const float* __restrict__ WSb, const float* __restrict__ Wv,
                        const float* __restrict__ bv, float* __restrict__ score) {
    int row = blockIdx.x * 4 + (threadIdx.x >> 6);  // 32768 rows
    int lane = threadIdx.x & 63;
    int b = row >> 9;
    float acc = 0.f;
#pragma unroll
    for (int q = 0; q < 4; q++) {
        int v = q * 64 + lane;
        float val = bf2f(WH[(size_t)row * 256 + v]) + bah[v] + WSb[b * 256 + v];
        acc += tanhf(val) * Wv[v];
    }
#pragma unroll
    for (int o = 32; o; o >>= 1) acc += __shfl_down(acc, o);
    if (lane == 0) score[row] = acc + bv[0];
}

__global__ __launch_bounds__(512) void k_softmax(const float* __restrict__ score, float* __restrict__ attn) {
    __shared__ float red[8];
    __shared__ float red2[8];
    int b = blockIdx.x, t = threadIdx.x;
    float x = score[b * 512 + t];
    float m = x;
#pragma unroll
    for (int o = 32; o; o >>= 1) m = fmaxf(m, __shfl_xor(m, o));
    if ((t & 63) == 0) red[t >> 6] = m;
    __syncthreads();
    if (t == 0) { float mm = red[0]; for (int i = 1; i < 8; i++) mm = fmaxf(mm, red[i]); red[0] = mm; }
    __syncthreads();
    m = red[0];
    float e = __expf(x - m);
    float s = e;
#pragma unroll
    for (int o = 32; o; o >>= 1) s += __shfl_xor(s, o);
    if ((t & 63) == 0) red2[t >> 6] = s;
    __syncthreads();
    if (t == 0) { float ss = 0.f; for (int i = 0; i < 8; i++) ss += red2[i]; red2[0] = ss; }
    __syncthreads();
    attn[b * 512 + t] = e / red2[0];
}

__global__ void k_attnout(const unsigned short* __restrict__ hs, const float* __restrict__ attn,
                          float* __restrict__ ao) {
    __shared__ float a_s[512];
    int b = blockIdx.x >> 2;
    int hcol = (blockIdx.x & 3) * 256 + threadIdx.x;
    a_s[threadIdx.x] = attn[b * 512 + threadIdx.x];
    a_s[256 + threadIdx.x] = attn[b * 512 + 256 + threadIdx.x];
    __syncthreads();
    float acc = 0.f;
    for (int s = 0; s < 512; s++)
        acc += bf2f(hs[((size_t)(b * 512 + s)) * 1024 + hcol]) * a_s[s];
    ao[b * 1024 + hcol] = acc;
}

__global__ void k_out(const float* __restrict__ fh, const float* __restrict__ ao,
                      const float* __restrict__ Wout, const float* __restrict__ bout,
                      float* __restrict__ out) {
    int t = threadIdx.x;
    if (t >= 128) return;
    int b = t >> 1, o = t & 1;
    float acc = bout[o];
    for (int k = 0; k < 512; k++) acc += fh[b * 512 + k] * Wout[k * 2 + o];
    for (int k = 0; k < 1024; k++) acc += ao[b * 1024 + k] * Wout[(512 + k) * 2 + o];
    out[b * 2 + o] = sigm(acc);
}

// ---------------- launch ----------------

extern "C" void kernel_launch(void* const* d_in, const int* in_sizes, int n_in,
                              void* d_out, int out_size, void* d_ws, size_t ws_size,
                              hipStream_t stream) {
    const float* text  = (const float*)d_in[0];
    const float* W_in  = (const float*)d_in[1];
    const float* b_in  = (const float*)d_in[2];
    const float* W_h   = (const float*)d_in[3];
    const float* b_h   = (const float*)d_in[4];
    const float* W_ah  = (const float*)d_in[5];
    const float* b_ah  = (const float*)d_in[6];
    const float* W_as  = (const float*)d_in[7];
    const float* b_as  = (const float*)d_in[8];
    const float* W_v   = (const float*)d_in[9];
    const float* b_v   = (const float*)d_in[10];
    const float* W_lo  = (const float*)d_in[11];
    const float* b_lo  = (const float*)d_in[12];
    const float* W_out = (const float*)d_in[13];
    const float* b_out = (const float*)d_in[14];
    float* out = (float*)d_out;

    char* ws = (char*)d_ws;
    size_t off = 0;
    auto alloc = [&](size_t bytes) {
        void* p = ws + off;
        off = (off + bytes + 255) & ~(size_t)255;
        return p;
    };
    // fixed buffers (~84 MB)
    unsigned short* WinT    = (unsigned short*)alloc((size_t)4096 * 768 * 2);
    unsigned short* WhPack  = (unsigned short*)alloc((size_t)4096 * 1024 * 2);
    unsigned short* WahT    = (unsigned short*)alloc((size_t)256 * 1024 * 2);
    float*          biassum = (float*)alloc(4096 * 4);
    unsigned short* hsbuf   = (unsigned short*)alloc((size_t)32768 * 1024 * 2);
    unsigned short* h_bf    = (unsigned short*)alloc((size_t)2 * 65536 * 2);
    float*          h_f32   = (float*)alloc(65536 * 4);
    float*          c_f32   = (float*)alloc(65536 * 4);
    float*          fh      = (float*)alloc(32768 * 4);
    float*          WSb     = (float*)alloc(16384 * 4);
    float*          score   = (float*)alloc(32768 * 4);
    float*          attn    = (float*)alloc(32768 * 4);
    float*          ao      = (float*)alloc(65536 * 4);

    // variable region: xg chunk while scanning; WHb afterwards (aliased)
    size_t remain = (ws_size > off + 4096) ? (ws_size - off - 4096) : 0;
    int c = 2;
    for (int cc = 512; cc >= 2; cc >>= 1) {
        size_t need = (size_t)64 * cc * 4096 * 2;
        size_t whb  = (size_t)32768 * 256 * 2;
        if ((need > whb ? need : whb) <= remain) { c = cc; break; }
    }
    int log2c = __builtin_ctz(c);
    unsigned short* xgc = (unsigned short*)alloc(1);  // rest of ws
    unsigned short* WHb = xgc;

    // prep
    dim3 tb(32, 8);
    k_transpose_bf16<<<dim3(4096 / 32, 768 / 32), tb, 0, stream>>>(W_in, WinT, 768, 4096);
    k_transpose_bf16<<<dim3(256 / 32, 1024 / 32), tb, 0, stream>>>(W_ah, WahT, 1024, 256);
    k_pack_wh<<<2048, 256, 0, stream>>>(W_h, WhPack);
    k_bias<<<16, 256, 0, stream>>>(b_in, b_h, biassum);
    hipMemsetAsync(h_bf, 0, (size_t)2 * 65536 * 2, stream);
    hipMemsetAsync(c_f32, 0, 65536 * 4, stream);

    // chunked scan: GEMM1 for c timesteps, then c LSTM steps
    int nch = 512 / c;
    for (int ch = 0; ch < nch; ch++) {
        k_gemm1<<<dim3(32, c / 2), 256, 0, stream>>>(text, WinT, xgc, ch * c, log2c);
        for (int tl = 0; tl < c; tl++) {
            int ts = ch * c + tl;
            const unsigned short* hin = h_bf + (size_t)(ts & 1) * 65536;
            unsigned short* hout = h_bf + (size_t)((ts + 1) & 1) * 65536;
            k_lstm_step<<<128, 512, 0, stream>>>(xgc, WhPack, biassum, hin, hout,
                                                 h_f32, c_f32, hsbuf, ts, tl, log2c);
        }
    }

    // tail
    k_fh<<<128, 256, 0, stream>>>(h_f32, W_lo, b_lo, fh);
    k_wsb<<<64, 256, 0, stream>>>(fh, W_as, b_as, WSb);
    k_gemm_bf16<<<dim3(2, 256), 256, 0, stream>>>(hsbuf, WahT, WHb, 32768, 256, 1024);
    k_score<<<8192, 256, 0, stream>>>(WHb, b_ah, WSb, W_v, b_v, score);
    k_softmax<<<64, 512, 0, stream>>>(score, attn);
    k_attnout<<<256, 256, 0, stream>>>(hsbuf, attn, ao);
    k_out<<<1, 128, 0, stream>>>(fh, ao, W_out, b_out, out);
}